// Round 13
// baseline (6092.920 us; speedup 1.0000x reference)
//
#include <hip/hip_runtime.h>
#include <hip/hip_bf16.h>

// ---------------------------------------------------------------------------
// 4-layer LSTM stack + inference BatchNorm, B=512 T=256 F=128, H=256/128/64/32
//  GEMM: pre-split bf16 hi/lo operands (3-pass MFMA = fp32-accurate), 64x64
//        tile, 256 threads (r7 body — measured 5.64 ms reference).
//  Rec:  layers 1-2 gate-split fp16 U/h (fdot2). r13 single change: U staged
//        into LDS — layer 2 fully (131 KB), layer 1 first 16/64 chunks
//        (128 KB) — cutting per-step L2 U traffic (0% / -25%). Read order
//        unchanged -> bit-identical numerics. layers 3-4 fp32 LDS U. Tc=256.
// ---------------------------------------------------------------------------

typedef __attribute__((ext_vector_type(8))) short short8;
typedef __attribute__((ext_vector_type(4))) float f32x4;
typedef _Float16 half_t;
typedef __attribute__((ext_vector_type(2))) _Float16 half2_t;

__device__ __forceinline__ short bf_hi(float v) {
    unsigned u = __builtin_bit_cast(unsigned, v);
    return (short)((u + 0x7FFFu + ((u >> 16) & 1u)) >> 16);   // RNE to bf16
}
__device__ __forceinline__ float bf_val(short s) {
    return __builtin_bit_cast(float, ((unsigned)(unsigned short)s) << 16);
}
__device__ __forceinline__ float fsig(float x)  { return 1.f / (1.f + __expf(-x)); }
__device__ __forceinline__ float ftanh(float x) { return 1.f - 2.f / (1.f + __expf(2.f * x)); }

__device__ __forceinline__ float fdot2(half2_t a, half2_t b, float c) {
#if defined(__has_builtin)
#if __has_builtin(__builtin_amdgcn_fdot2)
    return __builtin_amdgcn_fdot2(a, b, c, false);
#else
    return c + (float)a[0] * (float)b[0] + (float)a[1] * (float)b[1];
#endif
#else
    return c + (float)a[0] * (float)b[0] + (float)a[1] * (float)b[1];
#endif
}
__device__ __forceinline__ half2_t h2(unsigned u) { return __builtin_bit_cast(half2_t, u); }

// ---------------------------------------------------------------------------
// prep: W[k][c] fp32 -> hi/lo bf16, chunked [(k/8)*N4 + c][k%8]
// ---------------------------------------------------------------------------
__global__ void w_split(const float* __restrict__ W, short* __restrict__ hi,
                        short* __restrict__ lo, int K, int N4)
{
    int idx = blockIdx.x * 256 + threadIdx.x;
    if (idx < K * N4) {
        int k = idx / N4, c = idx - k * N4;
        float v = W[idx];
        short h = bf_hi(v);
        short l = bf_hi(v - bf_val(h));
        size_t o = ((size_t)(k >> 3) * N4 + c) * 8 + (k & 7);
        hi[o] = h; lo[o] = l;
    }
}

// prep: U fp32 -> fp16, chunked [(k/4)*H4 + c][k%4]   (layers 1-2)
__global__ void u_chunk_h(const float* __restrict__ U, half_t* __restrict__ Ut,
                          int H, int H4)
{
    int idx = blockIdx.x * 256 + threadIdx.x;
    if (idx < H * H4) {
        int k = idx / H4, c = idx - k * H4;
        Ut[((size_t)(k >> 2) * H4 + c) * 4 + (k & 3)] = (half_t)U[idx];
    }
}

// prep: U fp32 chunked (layers 3-4, LDS-persistent)
__global__ void u_chunk(const float* __restrict__ U, float* __restrict__ Ut,
                        int H, int H4)
{
    int idx = blockIdx.x * 256 + threadIdx.x;
    if (idx < H * H4) {
        int k = idx / H4, c = idx - k * H4;
        Ut[((size_t)(k >> 2) * H4 + c) * 4 + (k & 3)] = U[idx];
    }
}

// ---------------------------------------------------------------------------
// XW GEMM (r7 body): 64x64 tile, BK=32, 256 threads, pre-split operands.
// ---------------------------------------------------------------------------
template<bool AF32>
__global__ __launch_bounds__(256) void gemm_bf16(
    const void* __restrict__ Af, const void* __restrict__ AhiV,
    const void* __restrict__ AloV, size_t aRowStride,
    const short* __restrict__ Whc, const short* __restrict__ Wlc,
    const float* __restrict__ bias, float* __restrict__ C,
    int K, int N4, int Tc)
{
    __shared__ short Ah[4][64][8], Al[4][64][8], Wh[4][64][8], Wl[4][64][8];

    const int tid  = threadIdx.x;
    const int lane = tid & 63, wave = tid >> 6;
    const int r0 = blockIdx.x * 64, n0 = blockIdx.y * 64;

    const int akt = tid & 3, arow = tid >> 2;
    const int rr = r0 + arow;
    const int bb = rr / Tc, tc2 = rr - bb * Tc;
    const size_t aOff = (size_t)bb * aRowStride + (size_t)tc2 * K + (akt << 3);
    const int wkt = tid >> 6, wcol = tid & 63;
    const size_t wOff = ((size_t)wkt * N4 + n0 + wcol) * 8;

    f32x4 acc[4];
#pragma unroll
    for (int nt = 0; nt < 4; ++nt) acc[nt] = (f32x4){0.f, 0.f, 0.f, 0.f};

    const int frow = (wave << 4) | (lane & 15);
    const int fkb  = lane >> 4;
    const int bcol = lane & 15;

    const int nkt = K >> 5;
    for (int kt = 0; kt < nkt; ++kt) {
        if constexpr (AF32) {
            const float* ap = (const float*)Af + aOff + (size_t)kt * 32;
            float av[8];
            *(float4*)&av[0] = *(const float4*)(ap);
            *(float4*)&av[4] = *(const float4*)(ap + 4);
            short8 sh, sl;
#pragma unroll
            for (int e = 0; e < 8; ++e) {
                short h = bf_hi(av[e]); sh[e] = h;
                sl[e] = bf_hi(av[e] - bf_val(h));
            }
            *(short8*)&Ah[akt][arow][0] = sh;
            *(short8*)&Al[akt][arow][0] = sl;
        } else {
            *(short8*)&Ah[akt][arow][0] =
                *(const short8*)((const short*)AhiV + aOff + (size_t)kt * 32);
            *(short8*)&Al[akt][arow][0] =
                *(const short8*)((const short*)AloV + aOff + (size_t)kt * 32);
        }
        *(short8*)&Wh[wkt][wcol][0] = *(const short8*)(Whc + wOff + (size_t)kt * 4 * N4 * 8);
        *(short8*)&Wl[wkt][wcol][0] = *(const short8*)(Wlc + wOff + (size_t)kt * 4 * N4 * 8);
        __syncthreads();

        short8 a_h = *(const short8*)&Ah[fkb][frow][0];
        short8 a_l = *(const short8*)&Al[fkb][frow][0];
#pragma unroll
        for (int nt = 0; nt < 4; ++nt) {
            short8 b_h = *(const short8*)&Wh[fkb][nt * 16 + bcol][0];
            short8 b_l = *(const short8*)&Wl[fkb][nt * 16 + bcol][0];
            acc[nt] = __builtin_amdgcn_mfma_f32_16x16x32_bf16(a_h, b_h, acc[nt], 0, 0, 0);
            acc[nt] = __builtin_amdgcn_mfma_f32_16x16x32_bf16(a_l, b_h, acc[nt], 0, 0, 0);
            acc[nt] = __builtin_amdgcn_mfma_f32_16x16x32_bf16(a_h, b_l, acc[nt], 0, 0, 0);
        }
        __syncthreads();
    }

    const int crow0 = r0 + (wave << 4) + ((lane >> 4) << 2);
#pragma unroll
    for (int nt = 0; nt < 4; ++nt) {
        int col = n0 + nt * 16 + bcol;
        float bs = bias[col];
#pragma unroll
        for (int q = 0; q < 4; ++q)
            C[(size_t)(crow0 + q) * N4 + col] = acc[nt][q] + bs;
    }
}

// ---------------------------------------------------------------------------
// Recurrent kernel, fp16 U/h (layers 1-2). Gate-split (r7 structure).
// r13: first KLDS k-chunks of U staged in LDS (once), rest via r7's 4-deep
// global pipeline. Ascending-kc order preserved -> bit-identical numerics.
// ---------------------------------------------------------------------------
template<int H, int M, int G, int KLDS>
__global__ __launch_bounds__(H * G) void lstm_rec_h(
    const float* __restrict__ XW, const uint2* __restrict__ Uth,
    const float* __restrict__ bn_g, const float* __restrict__ bn_b,
    const float* __restrict__ bn_m, const float* __restrict__ bn_v,
    short* __restrict__ outHi, short* __restrict__ outLo, size_t oRowStride,
    float* __restrict__ h_ws, float* __restrict__ c_ws, int t0, int Tc)
{
    constexpr int TPB = H * G;
    constexpr int GPG = 4 / G;
    constexpr int NCH = H / 4;
    constexpr int H4  = 4 * H;
    static_assert(KLDS >= 1 && KLDS <= NCH, "");
    static_assert((NCH - KLDS) % 4 == 0, "");

    const int tid = threadIdx.x;
    const int j   = tid & (H - 1);
    const int g   = tid / H;
    const int b0  = blockIdx.x * M;
    const int cbase = g * GPG * H + j;

    __shared__ unsigned hsmh[M][H / 2];        // packed half2
    __shared__ float zx[G - 1][M][GPG][H];
    __shared__ uint2 Ush[KLDS * H4];           // staged U chunks 0..KLDS-1

    // one-time U stage (coalesced)
    for (int i = tid; i < KLDS * H4; i += TPB) Ush[i] = Uth[i];

    float scale = 0.f, shift = 0.f, cst[M];
    if (g == 0) {
        scale = bn_g[j] * rsqrtf(bn_v[j] + 1e-3f);
        shift = bn_b[j] - bn_m[j] * scale;
        if (t0 == 0) {
#pragma unroll
            for (int i = 0; i < M; ++i) cst[i] = 0.f;
        } else {
#pragma unroll
            for (int i = 0; i < M; ++i) cst[i] = c_ws[(size_t)(b0 + i) * H + j];
        }
    }
    if (t0 == 0) {
        for (int c = tid; c < M * H / 2; c += TPB) ((unsigned*)hsmh)[c] = 0u;
    } else {
        for (int c = tid; c < M * H; c += TPB) {
            int r = c / H, jj = c - r * H;
            ((half_t*)hsmh)[(size_t)r * H + jj] = (half_t)h_ws[(size_t)(b0 + r) * H + jj];
        }
    }
    __syncthreads();

    for (int tl = 0; tl < Tc; ++tl) {
        float xwv[M][GPG];
#pragma unroll
        for (int i = 0; i < M; ++i) {
            const float* xp = XW + ((size_t)(b0 + i) * Tc + tl) * H4 + cbase;
#pragma unroll
            for (int q = 0; q < GPG; ++q) xwv[i][q] = xp[(size_t)q * H];
        }

        float zp[M][GPG];
#pragma unroll
        for (int i = 0; i < M; ++i)
#pragma unroll
            for (int q = 0; q < GPG; ++q) zp[i][q] = 0.f;

        // ---- chunks 0..KLDS-1 from LDS ----
#pragma unroll 4
        for (int kc = 0; kc < KLDS; ++kc) {
            uint2 ub[GPG];
#pragma unroll
            for (int q = 0; q < GPG; ++q) ub[q] = Ush[kc * H4 + cbase + q * H];
#pragma unroll
            for (int i = 0; i < M; ++i) {
                uint2 hv = *(const uint2*)&hsmh[i][kc * 2];
                half2_t ha = h2(hv.x), hb = h2(hv.y);
#pragma unroll
                for (int q = 0; q < GPG; ++q) {
                    zp[i][q] = fdot2(ha, h2(ub[q].x), zp[i][q]);
                    zp[i][q] = fdot2(hb, h2(ub[q].y), zp[i][q]);
                }
            }
        }

        // ---- chunks KLDS..NCH-1 from global, 4-deep pipeline (r7) ----
        if constexpr (KLDS < NCH) {
            uint2 buf[4][GPG];
            auto loadC = [&](int s, int kc) {
                if (kc >= NCH) kc = KLDS;      // harmless tail wrap (discarded)
                const uint2* p = Uth + (size_t)kc * H4 + cbase;
#pragma unroll
                for (int q = 0; q < GPG; ++q) buf[s][q] = p[(size_t)q * H];
            };
            auto fmaC = [&](int s, int kc) {
#pragma unroll
                for (int i = 0; i < M; ++i) {
                    uint2 hv = *(const uint2*)&hsmh[i][kc * 2];
                    half2_t ha = h2(hv.x), hb = h2(hv.y);
#pragma unroll
                    for (int q = 0; q < GPG; ++q) {
                        zp[i][q] = fdot2(ha, h2(buf[s][q].x), zp[i][q]);
                        zp[i][q] = fdot2(hb, h2(buf[s][q].y), zp[i][q]);
                    }
                }
            };
            loadC(0, KLDS); loadC(1, KLDS + 1); loadC(2, KLDS + 2);
            for (int kc = KLDS; kc < NCH; kc += 4) {
                loadC(3, kc + 3); fmaC(0, kc);
                loadC(0, kc + 4); fmaC(1, kc + 1);
                loadC(1, kc + 5); fmaC(2, kc + 2);
                loadC(2, kc + 6); fmaC(3, kc + 3);
            }
        }

#pragma unroll
        for (int i = 0; i < M; ++i)
#pragma unroll
            for (int q = 0; q < GPG; ++q) zp[i][q] += xwv[i][q];

        if (g > 0) {
#pragma unroll
            for (int i = 0; i < M; ++i)
#pragma unroll
                for (int q = 0; q < GPG; ++q) zx[g - 1][i][q][j] = zp[i][q];
        }
        __syncthreads();

        if (g == 0) {
#pragma unroll
            for (int i = 0; i < M; ++i) {
                float zg[4];
#pragma unroll
                for (int gt = 0; gt < 4; ++gt) {
                    int grp = gt / GPG, q = gt - grp * GPG;
                    zg[gt] = (grp == 0) ? zp[i][q] : zx[grp - 1][i][q][j];
                }
                float ig = fsig(zg[0]);
                float fg = fsig(zg[1]);
                float gg = ftanh(zg[2]);
                float og = fsig(zg[3]);
                cst[i] = fg * cst[i] + ig * gg;
                float hv = og * ftanh(cst[i]);
                ((half_t*)hsmh)[(size_t)i * H + j] = (half_t)hv;
                float v = hv * scale + shift;
                short vh = bf_hi(v);
                short vl = bf_hi(v - bf_val(vh));
                size_t o = (size_t)(b0 + i) * oRowStride + (size_t)tl * H + j;
                outHi[o] = vh; outLo[o] = vl;
            }
        }
        __syncthreads();
    }

    if (g == 0 && t0 + Tc < 256) {
#pragma unroll
        for (int i = 0; i < M; ++i) {
            size_t r = (size_t)(b0 + i);
            h_ws[r * H + j] = (float)((half_t*)hsmh)[(size_t)i * H + j];
            c_ws[r * H + j] = cst[i];
        }
    }
}

// ---------------------------------------------------------------------------
// Recurrent kernel, fp32 + LDS-persistent U (layers 3-4).
// ---------------------------------------------------------------------------
template<int H, int M, int G, bool LAST>
__global__ __launch_bounds__(H * G) void lstm_rec32(
    const float* __restrict__ XW, const float* __restrict__ Ut,
    const float* __restrict__ bn_g, const float* __restrict__ bn_b,
    const float* __restrict__ bn_m, const float* __restrict__ bn_v,
    short* __restrict__ outHi, short* __restrict__ outLo,
    float* __restrict__ outF, size_t oRowStride,
    float* __restrict__ h_ws, float* __restrict__ c_ws, int t0, int Tc)
{
    constexpr int TPB = H * G;
    constexpr int GPG = 4 / G;
    constexpr int NCH = H / 4;
    constexpr int H4  = 4 * H;

    const int tid = threadIdx.x;
    const int j   = tid & (H - 1);
    const int g   = tid / H;
    const int b0  = blockIdx.x * M;
    const int cbase = g * GPG * H + j;

    __shared__ float hsm[M][H];
    __shared__ float zx[G - 1][M][GPG][H];
    __shared__ float Us[4 * H * H];

    for (int i = tid * 4; i < 4 * H * H; i += TPB * 4)
        *(float4*)&Us[i] = *(const float4*)&Ut[i];

    float scale = 0.f, shift = 0.f, cst[M];
    if (g == 0) {
        scale = bn_g[j] * rsqrtf(bn_v[j] + 1e-3f);
        shift = bn_b[j] - bn_m[j] * scale;
        if (t0 == 0) {
#pragma unroll
            for (int i = 0; i < M; ++i) cst[i] = 0.f;
        } else {
#pragma unroll
            for (int i = 0; i < M; ++i) cst[i] = c_ws[(size_t)(b0 + i) * H + j];
        }
    }
    if (t0 == 0) {
        for (int c = tid; c < M * H; c += TPB) ((float*)hsm)[c] = 0.f;
    } else {
        for (int c = tid; c < M * H; c += TPB) {
            int r = c / H, jj = c - r * H;
            ((float*)hsm)[c] = h_ws[(size_t)(b0 + r) * H + jj];
        }
    }
    __syncthreads();

    for (int tl = 0; tl < Tc; ++tl) {
        float xwv[M][GPG];
#pragma unroll
        for (int i = 0; i < M; ++i) {
            const float* xp = XW + ((size_t)(b0 + i) * Tc + tl) * H4 + cbase;
#pragma unroll
            for (int q = 0; q < GPG; ++q) xwv[i][q] = xp[(size_t)q * H];
        }

        float zp[M][GPG];
#pragma unroll
        for (int i = 0; i < M; ++i)
#pragma unroll
            for (int q = 0; q < GPG; ++q) zp[i][q] = 0.f;

#pragma unroll
        for (int kc = 0; kc < NCH; ++kc) {
            float4 ub[GPG];
#pragma unroll
            for (int q = 0; q < GPG; ++q)
                ub[q] = *(const float4*)&Us[((size_t)kc * H4 + cbase + q * H) * 4];
#pragma unroll
            for (int i = 0; i < M; ++i) {
                const float4 h4 = *(const float4*)&hsm[i][kc * 4];
#pragma unroll
                for (int q = 0; q < GPG; ++q)
                    zp[i][q] += h4.x * ub[q].x + h4.y * ub[q].y
                              + h4.z * ub[q].z + h4.w * ub[q].w;
            }
        }

#pragma unroll
        for (int i = 0; i < M; ++i)
#pragma unroll
            for (int q = 0; q < GPG; ++q) zp[i][q] += xwv[i][q];

        if (g > 0) {
#pragma unroll
            for (int i = 0; i < M; ++i)
#pragma unroll
                for (int q = 0; q < GPG; ++q) zx[g - 1][i][q][j] = zp[i][q];
        }
        __syncthreads();

        if (g == 0) {
            const int t = t0 + tl;
#pragma unroll
            for (int i = 0; i < M; ++i) {
                float zg[4];
#pragma unroll
                for (int gt = 0; gt < 4; ++gt) {
                    int grp = gt / GPG, q = gt - grp * GPG;
                    zg[gt] = (grp == 0) ? zp[i][q] : zx[grp - 1][i][q][j];
                }
                float ig = fsig(zg[0]);
                float fg = fsig(zg[1]);
                float gg = ftanh(zg[2]);
                float og = fsig(zg[3]);
                cst[i] = fg * cst[i] + ig * gg;
                float hv = og * ftanh(cst[i]);
                hsm[i][j] = hv;
                float v = hv * scale + shift;
                size_t r = (size_t)(b0 + i);
                if constexpr (!LAST) {
                    short vh = bf_hi(v);
                    short vl = bf_hi(v - bf_val(vh));
                    size_t o = r * oRowStride + (size_t)tl * H + j;
                    outHi[o] = vh; outLo[o] = vl;
                } else {
                    if (t == 255) outF[r * H + j] = v;
                }
            }
        }
        __syncthreads();
    }

    if (g == 0 && t0 + Tc < 256) {
#pragma unroll
        for (int i = 0; i < M; ++i) {
            size_t r = (size_t)(b0 + i);
            h_ws[r * H + j] = hsm[i][j];
            c_ws[r * H + j] = cst[i];
        }
    }
}

// ---------------------------------------------------------------------------
extern "C" void kernel_launch(void* const* d_in, const int* in_sizes, int n_in,
                              void* d_out, int out_size, void* d_ws, size_t ws_size,
                              hipStream_t stream)
{
    const float* state = (const float*)d_in[0];
    const float *W[4], *U[4], *bi[4], *g[4], *be[4], *mm[4], *vv[4];
    for (int l = 0; l < 4; ++l) {
        W[l]  = (const float*)d_in[1 + 7 * l + 0];
        U[l]  = (const float*)d_in[1 + 7 * l + 1];
        bi[l] = (const float*)d_in[1 + 7 * l + 2];
        g[l]  = (const float*)d_in[1 + 7 * l + 3];
        be[l] = (const float*)d_in[1 + 7 * l + 4];
        mm[l] = (const float*)d_in[1 + 7 * l + 5];
        vv[l] = (const float*)d_in[1 + 7 * l + 6];
    }
    const int HS[4]  = {256, 128, 64, 32};
    const int FIN[4] = {128, 256, 128, 64};

    // ---- fixed-buffer byte sizes ----------------------------------------
    size_t wB[4], uthB[2], utB[2], hB[4];
    size_t fixed = 0;
    for (int l = 0; l < 4; ++l) { wB[l] = (size_t)FIN[l] * 4 * HS[l] * 2; fixed += 2 * ((wB[l] + 15) & ~15ull); }
    for (int l = 0; l < 2; ++l) { uthB[l] = (size_t)4 * HS[l] * HS[l] * 2; fixed += (uthB[l] + 15) & ~15ull; }
    for (int l = 0; l < 2; ++l) { utB[l] = (size_t)4 * HS[l + 2] * HS[l + 2] * 4; fixed += (utB[l] + 15) & ~15ull; }
    for (int l = 0; l < 4; ++l) { hB[l] = (size_t)512 * HS[l] * 4; fixed += 2 * ((hB[l] + 15) & ~15ull); }
    fixed += 1024;  // alignment slack

    auto xwBytes  = [&](size_t tc) { return (size_t)512 * tc * 1024 * 4; };
    auto actBytes = [&](size_t t)  { return (size_t)512 * t * (256 + 128 + 64) * 2 * 2; };

    int Tc = 256; bool fullAct = true;
    while (Tc > 8 && fixed + xwBytes(Tc) + actBytes(256) > ws_size) Tc >>= 1;
    if (fixed + xwBytes(Tc) + actBytes(256) > ws_size) {
        fullAct = false; Tc = 32;
        while (Tc > 1 && fixed + xwBytes(Tc) + actBytes(Tc) > ws_size) Tc >>= 1;
    }
    int nc = 256 / Tc;
    size_t Tact = fullAct ? 256 : (size_t)Tc;

    // ---- allocate --------------------------------------------------------
    size_t off = 0;
    auto alloc = [&](size_t bytes) -> char* {
        char* p = (char*)d_ws + off;
        off = (off + bytes + 15) & ~15ull;
        return p;
    };
    float* xw = (float*)alloc(xwBytes(Tc));
    short *actHi[4], *actLo[4];
    actHi[0] = actLo[0] = nullptr;
    for (int l = 1; l < 4; ++l) {
        size_t b = (size_t)512 * Tact * FIN[l] * 2;
        actHi[l] = (short*)alloc(b);
        actLo[l] = (short*)alloc(b);
    }
    float *hb[4], *cb[4];
    for (int l = 0; l < 4; ++l) { hb[l] = (float*)alloc(hB[l]); cb[l] = (float*)alloc(hB[l]); }
    half_t* uth[2]; float* ut[2];
    for (int l = 0; l < 2; ++l) uth[l] = (half_t*)alloc(uthB[l]);
    for (int l = 0; l < 2; ++l) ut[l] = (float*)alloc(utB[l]);
    short *whi[4], *wlo[4];
    for (int l = 0; l < 4; ++l) { whi[l] = (short*)alloc(wB[l]); wlo[l] = (short*)alloc(wB[l]); }

    // ---- one-time prep ---------------------------------------------------
    for (int l = 0; l < 4; ++l) {
        int n = FIN[l] * 4 * HS[l];
        w_split<<<dim3((n + 255) / 256), dim3(256), 0, stream>>>(W[l], whi[l], wlo[l], FIN[l], 4 * HS[l]);
    }
    for (int l = 0; l < 2; ++l) {
        int n = HS[l] * 4 * HS[l];
        u_chunk_h<<<dim3((n + 255) / 256), dim3(256), 0, stream>>>(U[l], uth[l], HS[l], 4 * HS[l]);
    }
    for (int l = 0; l < 2; ++l) {
        int n = HS[l + 2] * 4 * HS[l + 2];
        u_chunk<<<dim3((n + 255) / 256), dim3(256), 0, stream>>>(U[l + 2], ut[l], HS[l + 2], 4 * HS[l + 2]);
    }

    // ---- time-chunk-interleaved layer sweep -----------------------------
    for (int c = 0; c < nc; ++c) {
        int t0 = c * Tc;
        for (int l = 0; l < 4; ++l) {
            int K = FIN[l], N4 = 4 * HS[l];
            dim3 gg((512 * Tc) / 64, N4 / 64);

            if (l == 0) {
                const float* Abase = state + (size_t)t0 * 128;
                gemm_bf16<true><<<gg, dim3(256), 0, stream>>>(
                    (const void*)Abase, nullptr, nullptr, (size_t)256 * 128,
                    whi[0], wlo[0], bi[0], xw, K, N4, Tc);
            } else {
                size_t aOff = fullAct ? (size_t)t0 * K : 0;
                size_t aStride = fullAct ? (size_t)256 * K : (size_t)Tc * K;
                gemm_bf16<false><<<gg, dim3(256), 0, stream>>>(
                    nullptr, (const void*)(actHi[l] + aOff), (const void*)(actLo[l] + aOff),
                    aStride, whi[l], wlo[l], bi[l], xw, K, N4, Tc);
            }

            short *oHi = nullptr, *oLo = nullptr;
            size_t oStride = 0;
            if (l < 3) {
                size_t oOff = fullAct ? (size_t)t0 * HS[l] : 0;
                oStride = fullAct ? (size_t)256 * HS[l] : (size_t)Tc * HS[l];
                oHi = actHi[l + 1] + oOff;
                oLo = actLo[l + 1] + oOff;
            }

            if (l == 0)
                lstm_rec_h<256, 4, 2, 16><<<dim3(128), dim3(512), 0, stream>>>(
                    xw, (const uint2*)uth[0], g[0], be[0], mm[0], vv[0],
                    oHi, oLo, oStride, hb[0], cb[0], t0, Tc);
            else if (l == 1)
                lstm_rec_h<128, 4, 4, 32><<<dim3(128), dim3(512), 0, stream>>>(
                    xw, (const uint2*)uth[1], g[1], be[1], mm[1], vv[1],
                    oHi, oLo, oStride, hb[1], cb[1], t0, Tc);
            else if (l == 2)
                lstm_rec32<64, 4, 4, false><<<dim3(128), dim3(256), 0, stream>>>(
                    xw, ut[0], g[2], be[2], mm[2], vv[2],
                    oHi, oLo, nullptr, oStride, hb[2], cb[2], t0, Tc);
            else
                lstm_rec32<32, 4, 4, true><<<dim3(128), dim3(128), 0, stream>>>(
                    xw, ut[1], g[3], be[3], mm[3], vv[3],
                    nullptr, nullptr, (float*)d_out, 0, hb[3], cb[3], t0, Tc);
        }
    }
}

// Round 14
// 5631.218 us; speedup vs baseline: 1.0820x; 1.0820x over previous
//
#include <hip/hip_runtime.h>
#include <hip/hip_bf16.h>

// ---------------------------------------------------------------------------
// 4-layer LSTM stack + inference BatchNorm, B=512 T=256 F=128, H=256/128/64/32
//  r14 = MEASUREMENT ROUND: exact r7 body (5.64 ms reference); each rec
//  dispatch launched TWICE (idempotent at nc==1) so Δdur vs 5.64 = rec_total.
//  This resolves the GEMM/rec split that rocprof (13/13 parse failures)
//  never delivered.
// ---------------------------------------------------------------------------

typedef __attribute__((ext_vector_type(8))) short short8;
typedef __attribute__((ext_vector_type(4))) float f32x4;
typedef _Float16 half_t;
typedef __attribute__((ext_vector_type(2))) _Float16 half2_t;

__device__ __forceinline__ short bf_hi(float v) {
    unsigned u = __builtin_bit_cast(unsigned, v);
    return (short)((u + 0x7FFFu + ((u >> 16) & 1u)) >> 16);   // RNE to bf16
}
__device__ __forceinline__ float bf_val(short s) {
    return __builtin_bit_cast(float, ((unsigned)(unsigned short)s) << 16);
}
__device__ __forceinline__ float fsig(float x)  { return 1.f / (1.f + __expf(-x)); }
__device__ __forceinline__ float ftanh(float x) { return 1.f - 2.f / (1.f + __expf(2.f * x)); }

__device__ __forceinline__ float fdot2(half2_t a, half2_t b, float c) {
#if defined(__has_builtin)
#if __has_builtin(__builtin_amdgcn_fdot2)
    return __builtin_amdgcn_fdot2(a, b, c, false);
#else
    return c + (float)a[0] * (float)b[0] + (float)a[1] * (float)b[1];
#endif
#else
    return c + (float)a[0] * (float)b[0] + (float)a[1] * (float)b[1];
#endif
}
__device__ __forceinline__ half2_t h2(unsigned u) { return __builtin_bit_cast(half2_t, u); }

// ---------------------------------------------------------------------------
// prep: W[k][c] fp32 -> hi/lo bf16, chunked [(k/8)*N4 + c][k%8]
// ---------------------------------------------------------------------------
__global__ void w_split(const float* __restrict__ W, short* __restrict__ hi,
                        short* __restrict__ lo, int K, int N4)
{
    int idx = blockIdx.x * 256 + threadIdx.x;
    if (idx < K * N4) {
        int k = idx / N4, c = idx - k * N4;
        float v = W[idx];
        short h = bf_hi(v);
        short l = bf_hi(v - bf_val(h));
        size_t o = ((size_t)(k >> 3) * N4 + c) * 8 + (k & 7);
        hi[o] = h; lo[o] = l;
    }
}

// prep: U fp32 -> fp16, chunked [(k/4)*H4 + c][k%4]   (layers 1-2)
__global__ void u_chunk_h(const float* __restrict__ U, half_t* __restrict__ Ut,
                          int H, int H4)
{
    int idx = blockIdx.x * 256 + threadIdx.x;
    if (idx < H * H4) {
        int k = idx / H4, c = idx - k * H4;
        Ut[((size_t)(k >> 2) * H4 + c) * 4 + (k & 3)] = (half_t)U[idx];
    }
}

// prep: U fp32 chunked (layers 3-4, LDS-persistent)
__global__ void u_chunk(const float* __restrict__ U, float* __restrict__ Ut,
                        int H, int H4)
{
    int idx = blockIdx.x * 256 + threadIdx.x;
    if (idx < H * H4) {
        int k = idx / H4, c = idx - k * H4;
        Ut[((size_t)(k >> 2) * H4 + c) * 4 + (k & 3)] = U[idx];
    }
}

// ---------------------------------------------------------------------------
// XW GEMM (r7 body): 64x64 tile, BK=32, 256 threads, pre-split operands.
// ---------------------------------------------------------------------------
template<bool AF32>
__global__ __launch_bounds__(256) void gemm_bf16(
    const void* __restrict__ Af, const void* __restrict__ AhiV,
    const void* __restrict__ AloV, size_t aRowStride,
    const short* __restrict__ Whc, const short* __restrict__ Wlc,
    const float* __restrict__ bias, float* __restrict__ C,
    int K, int N4, int Tc)
{
    __shared__ short Ah[4][64][8], Al[4][64][8], Wh[4][64][8], Wl[4][64][8];

    const int tid  = threadIdx.x;
    const int lane = tid & 63, wave = tid >> 6;
    const int r0 = blockIdx.x * 64, n0 = blockIdx.y * 64;

    const int akt = tid & 3, arow = tid >> 2;
    const int rr = r0 + arow;
    const int bb = rr / Tc, tc2 = rr - bb * Tc;
    const size_t aOff = (size_t)bb * aRowStride + (size_t)tc2 * K + (akt << 3);
    const int wkt = tid >> 6, wcol = tid & 63;
    const size_t wOff = ((size_t)wkt * N4 + n0 + wcol) * 8;

    f32x4 acc[4];
#pragma unroll
    for (int nt = 0; nt < 4; ++nt) acc[nt] = (f32x4){0.f, 0.f, 0.f, 0.f};

    const int frow = (wave << 4) | (lane & 15);
    const int fkb  = lane >> 4;
    const int bcol = lane & 15;

    const int nkt = K >> 5;
    for (int kt = 0; kt < nkt; ++kt) {
        if constexpr (AF32) {
            const float* ap = (const float*)Af + aOff + (size_t)kt * 32;
            float av[8];
            *(float4*)&av[0] = *(const float4*)(ap);
            *(float4*)&av[4] = *(const float4*)(ap + 4);
            short8 sh, sl;
#pragma unroll
            for (int e = 0; e < 8; ++e) {
                short h = bf_hi(av[e]); sh[e] = h;
                sl[e] = bf_hi(av[e] - bf_val(h));
            }
            *(short8*)&Ah[akt][arow][0] = sh;
            *(short8*)&Al[akt][arow][0] = sl;
        } else {
            *(short8*)&Ah[akt][arow][0] =
                *(const short8*)((const short*)AhiV + aOff + (size_t)kt * 32);
            *(short8*)&Al[akt][arow][0] =
                *(const short8*)((const short*)AloV + aOff + (size_t)kt * 32);
        }
        *(short8*)&Wh[wkt][wcol][0] = *(const short8*)(Whc + wOff + (size_t)kt * 4 * N4 * 8);
        *(short8*)&Wl[wkt][wcol][0] = *(const short8*)(Wlc + wOff + (size_t)kt * 4 * N4 * 8);
        __syncthreads();

        short8 a_h = *(const short8*)&Ah[fkb][frow][0];
        short8 a_l = *(const short8*)&Al[fkb][frow][0];
#pragma unroll
        for (int nt = 0; nt < 4; ++nt) {
            short8 b_h = *(const short8*)&Wh[fkb][nt * 16 + bcol][0];
            short8 b_l = *(const short8*)&Wl[fkb][nt * 16 + bcol][0];
            acc[nt] = __builtin_amdgcn_mfma_f32_16x16x32_bf16(a_h, b_h, acc[nt], 0, 0, 0);
            acc[nt] = __builtin_amdgcn_mfma_f32_16x16x32_bf16(a_l, b_h, acc[nt], 0, 0, 0);
            acc[nt] = __builtin_amdgcn_mfma_f32_16x16x32_bf16(a_h, b_l, acc[nt], 0, 0, 0);
        }
        __syncthreads();
    }

    const int crow0 = r0 + (wave << 4) + ((lane >> 4) << 2);
#pragma unroll
    for (int nt = 0; nt < 4; ++nt) {
        int col = n0 + nt * 16 + bcol;
        float bs = bias[col];
#pragma unroll
        for (int q = 0; q < 4; ++q)
            C[(size_t)(crow0 + q) * N4 + col] = acc[nt][q] + bs;
    }
}

// ---------------------------------------------------------------------------
// Recurrent kernel, fp16 U/h (layers 1-2). Gate-split, 4-deep pipeline (r7).
// ---------------------------------------------------------------------------
template<int H, int M, int G>
__global__ __launch_bounds__(H * G) void lstm_rec_h(
    const float* __restrict__ XW, const uint2* __restrict__ Uth,
    const float* __restrict__ bn_g, const float* __restrict__ bn_b,
    const float* __restrict__ bn_m, const float* __restrict__ bn_v,
    short* __restrict__ outHi, short* __restrict__ outLo, size_t oRowStride,
    float* __restrict__ h_ws, float* __restrict__ c_ws, int t0, int Tc)
{
    constexpr int TPB = H * G;
    constexpr int GPG = 4 / G;
    constexpr int NCH = H / 4;
    constexpr int H4  = 4 * H;

    const int tid = threadIdx.x;
    const int j   = tid & (H - 1);
    const int g   = tid / H;
    const int b0  = blockIdx.x * M;
    const int cbase = g * GPG * H + j;

    __shared__ unsigned hsmh[M][H / 2];        // packed half2
    __shared__ float zx[G - 1][M][GPG][H];

    float scale = 0.f, shift = 0.f, cst[M];
    if (g == 0) {
        scale = bn_g[j] * rsqrtf(bn_v[j] + 1e-3f);
        shift = bn_b[j] - bn_m[j] * scale;
        if (t0 == 0) {
#pragma unroll
            for (int i = 0; i < M; ++i) cst[i] = 0.f;
        } else {
#pragma unroll
            for (int i = 0; i < M; ++i) cst[i] = c_ws[(size_t)(b0 + i) * H + j];
        }
    }
    if (t0 == 0) {
        for (int c = tid; c < M * H / 2; c += TPB) ((unsigned*)hsmh)[c] = 0u;
    } else {
        for (int c = tid; c < M * H; c += TPB) {
            int r = c / H, jj = c - r * H;
            ((half_t*)hsmh)[(size_t)r * H + jj] = (half_t)h_ws[(size_t)(b0 + r) * H + jj];
        }
    }
    __syncthreads();

    for (int tl = 0; tl < Tc; ++tl) {
        float xwv[M][GPG];
#pragma unroll
        for (int i = 0; i < M; ++i) {
            const float* xp = XW + ((size_t)(b0 + i) * Tc + tl) * H4 + cbase;
#pragma unroll
            for (int q = 0; q < GPG; ++q) xwv[i][q] = xp[(size_t)q * H];
        }

        float zp[M][GPG];
#pragma unroll
        for (int i = 0; i < M; ++i)
#pragma unroll
            for (int q = 0; q < GPG; ++q) zp[i][q] = 0.f;

        uint2 buf[4][GPG];
        auto loadC = [&](int s, int kc) {
            if (kc >= NCH) kc -= NCH;          // harmless tail wrap
            const uint2* p = Uth + (size_t)kc * H4 + cbase;
#pragma unroll
            for (int q = 0; q < GPG; ++q) buf[s][q] = p[(size_t)q * H];
        };
        auto fmaC = [&](int s, int kc) {
#pragma unroll
            for (int i = 0; i < M; ++i) {
                uint2 hv = *(const uint2*)&hsmh[i][kc * 2];
                half2_t ha = h2(hv.x);
                half2_t hb = h2(hv.y);
#pragma unroll
                for (int q = 0; q < GPG; ++q) {
                    half2_t ua = h2(buf[s][q].x);
                    half2_t ub = h2(buf[s][q].y);
                    zp[i][q] = fdot2(ha, ua, zp[i][q]);
                    zp[i][q] = fdot2(hb, ub, zp[i][q]);
                }
            }
        };
        loadC(0, 0); loadC(1, 1); loadC(2, 2);
        for (int kc = 0; kc < NCH; kc += 4) {
            loadC(3, kc + 3); fmaC(0, kc);
            loadC(0, kc + 4); fmaC(1, kc + 1);
            loadC(1, kc + 5); fmaC(2, kc + 2);
            loadC(2, kc + 6); fmaC(3, kc + 3);
        }

#pragma unroll
        for (int i = 0; i < M; ++i)
#pragma unroll
            for (int q = 0; q < GPG; ++q) zp[i][q] += xwv[i][q];

        if (g > 0) {
#pragma unroll
            for (int i = 0; i < M; ++i)
#pragma unroll
                for (int q = 0; q < GPG; ++q) zx[g - 1][i][q][j] = zp[i][q];
        }
        __syncthreads();

        if (g == 0) {
#pragma unroll
            for (int i = 0; i < M; ++i) {
                float zg[4];
#pragma unroll
                for (int gt = 0; gt < 4; ++gt) {
                    int grp = gt / GPG, q = gt - grp * GPG;
                    zg[gt] = (grp == 0) ? zp[i][q] : zx[grp - 1][i][q][j];
                }
                float ig = fsig(zg[0]);
                float fg = fsig(zg[1]);
                float gg = ftanh(zg[2]);
                float og = fsig(zg[3]);
                cst[i] = fg * cst[i] + ig * gg;
                float hv = og * ftanh(cst[i]);
                ((half_t*)hsmh)[(size_t)i * H + j] = (half_t)hv;
                float v = hv * scale + shift;
                short vh = bf_hi(v);
                short vl = bf_hi(v - bf_val(vh));
                size_t o = (size_t)(b0 + i) * oRowStride + (size_t)tl * H + j;
                outHi[o] = vh; outLo[o] = vl;
            }
        }
        __syncthreads();
    }

    if (g == 0 && t0 + Tc < 256) {
#pragma unroll
        for (int i = 0; i < M; ++i) {
            size_t r = (size_t)(b0 + i);
            h_ws[r * H + j] = (float)((half_t*)hsmh)[(size_t)i * H + j];
            c_ws[r * H + j] = cst[i];
        }
    }
}

// ---------------------------------------------------------------------------
// Recurrent kernel, fp32 + LDS-persistent U (layers 3-4).
// ---------------------------------------------------------------------------
template<int H, int M, int G, bool LAST>
__global__ __launch_bounds__(H * G) void lstm_rec32(
    const float* __restrict__ XW, const float* __restrict__ Ut,
    const float* __restrict__ bn_g, const float* __restrict__ bn_b,
    const float* __restrict__ bn_m, const float* __restrict__ bn_v,
    short* __restrict__ outHi, short* __restrict__ outLo,
    float* __restrict__ outF, size_t oRowStride,
    float* __restrict__ h_ws, float* __restrict__ c_ws, int t0, int Tc)
{
    constexpr int TPB = H * G;
    constexpr int GPG = 4 / G;
    constexpr int NCH = H / 4;
    constexpr int H4  = 4 * H;

    const int tid = threadIdx.x;
    const int j   = tid & (H - 1);
    const int g   = tid / H;
    const int b0  = blockIdx.x * M;
    const int cbase = g * GPG * H + j;

    __shared__ float hsm[M][H];
    __shared__ float zx[G - 1][M][GPG][H];
    __shared__ float Us[4 * H * H];

    for (int i = tid * 4; i < 4 * H * H; i += TPB * 4)
        *(float4*)&Us[i] = *(const float4*)&Ut[i];

    float scale = 0.f, shift = 0.f, cst[M];
    if (g == 0) {
        scale = bn_g[j] * rsqrtf(bn_v[j] + 1e-3f);
        shift = bn_b[j] - bn_m[j] * scale;
        if (t0 == 0) {
#pragma unroll
            for (int i = 0; i < M; ++i) cst[i] = 0.f;
        } else {
#pragma unroll
            for (int i = 0; i < M; ++i) cst[i] = c_ws[(size_t)(b0 + i) * H + j];
        }
    }
    if (t0 == 0) {
        for (int c = tid; c < M * H; c += TPB) ((float*)hsm)[c] = 0.f;
    } else {
        for (int c = tid; c < M * H; c += TPB) {
            int r = c / H, jj = c - r * H;
            ((float*)hsm)[c] = h_ws[(size_t)(b0 + r) * H + jj];
        }
    }
    __syncthreads();

    for (int tl = 0; tl < Tc; ++tl) {
        float xwv[M][GPG];
#pragma unroll
        for (int i = 0; i < M; ++i) {
            const float* xp = XW + ((size_t)(b0 + i) * Tc + tl) * H4 + cbase;
#pragma unroll
            for (int q = 0; q < GPG; ++q) xwv[i][q] = xp[(size_t)q * H];
        }

        float zp[M][GPG];
#pragma unroll
        for (int i = 0; i < M; ++i)
#pragma unroll
            for (int q = 0; q < GPG; ++q) zp[i][q] = 0.f;

#pragma unroll
        for (int kc = 0; kc < NCH; ++kc) {
            float4 ub[GPG];
#pragma unroll
            for (int q = 0; q < GPG; ++q)
                ub[q] = *(const float4*)&Us[((size_t)kc * H4 + cbase + q * H) * 4];
#pragma unroll
            for (int i = 0; i < M; ++i) {
                const float4 h4 = *(const float4*)&hsm[i][kc * 4];
#pragma unroll
                for (int q = 0; q < GPG; ++q)
                    zp[i][q] += h4.x * ub[q].x + h4.y * ub[q].y
                              + h4.z * ub[q].z + h4.w * ub[q].w;
            }
        }

#pragma unroll
        for (int i = 0; i < M; ++i)
#pragma unroll
            for (int q = 0; q < GPG; ++q) zp[i][q] += xwv[i][q];

        if (g > 0) {
#pragma unroll
            for (int i = 0; i < M; ++i)
#pragma unroll
                for (int q = 0; q < GPG; ++q) zx[g - 1][i][q][j] = zp[i][q];
        }
        __syncthreads();

        if (g == 0) {
            const int t = t0 + tl;
#pragma unroll
            for (int i = 0; i < M; ++i) {
                float zg[4];
#pragma unroll
                for (int gt = 0; gt < 4; ++gt) {
                    int grp = gt / GPG, q = gt - grp * GPG;
                    zg[gt] = (grp == 0) ? zp[i][q] : zx[grp - 1][i][q][j];
                }
                float ig = fsig(zg[0]);
                float fg = fsig(zg[1]);
                float gg = ftanh(zg[2]);
                float og = fsig(zg[3]);
                cst[i] = fg * cst[i] + ig * gg;
                float hv = og * ftanh(cst[i]);
                hsm[i][j] = hv;
                float v = hv * scale + shift;
                size_t r = (size_t)(b0 + i);
                if constexpr (!LAST) {
                    short vh = bf_hi(v);
                    short vl = bf_hi(v - bf_val(vh));
                    size_t o = r * oRowStride + (size_t)tl * H + j;
                    outHi[o] = vh; outLo[o] = vl;
                } else {
                    if (t == 255) outF[r * H + j] = v;
                }
            }
        }
        __syncthreads();
    }

    if (g == 0 && t0 + Tc < 256) {
#pragma unroll
        for (int i = 0; i < M; ++i) {
            size_t r = (size_t)(b0 + i);
            h_ws[r * H + j] = hsm[i][j];
            c_ws[r * H + j] = cst[i];
        }
    }
}

// ---------------------------------------------------------------------------
extern "C" void kernel_launch(void* const* d_in, const int* in_sizes, int n_in,
                              void* d_out, int out_size, void* d_ws, size_t ws_size,
                              hipStream_t stream)
{
    const float* state = (const float*)d_in[0];
    const float *W[4], *U[4], *bi[4], *g[4], *be[4], *mm[4], *vv[4];
    for (int l = 0; l < 4; ++l) {
        W[l]  = (const float*)d_in[1 + 7 * l + 0];
        U[l]  = (const float*)d_in[1 + 7 * l + 1];
        bi[l] = (const float*)d_in[1 + 7 * l + 2];
        g[l]  = (const float*)d_in[1 + 7 * l + 3];
        be[l] = (const float*)d_in[1 + 7 * l + 4];
        mm[l] = (const float*)d_in[1 + 7 * l + 5];
        vv[l] = (const float*)d_in[1 + 7 * l + 6];
    }
    const int HS[4]  = {256, 128, 64, 32};
    const int FIN[4] = {128, 256, 128, 64};

    // ---- fixed-buffer byte sizes ----------------------------------------
    size_t wB[4], uthB[2], utB[2], hB[4];
    size_t fixed = 0;
    for (int l = 0; l < 4; ++l) { wB[l] = (size_t)FIN[l] * 4 * HS[l] * 2; fixed += 2 * ((wB[l] + 15) & ~15ull); }
    for (int l = 0; l < 2; ++l) { uthB[l] = (size_t)4 * HS[l] * HS[l] * 2; fixed += (uthB[l] + 15) & ~15ull; }
    for (int l = 0; l < 2; ++l) { utB[l] = (size_t)4 * HS[l + 2] * HS[l + 2] * 4; fixed += (utB[l] + 15) & ~15ull; }
    for (int l = 0; l < 4; ++l) { hB[l] = (size_t)512 * HS[l] * 4; fixed += 2 * ((hB[l] + 15) & ~15ull); }
    fixed += 1024;  // alignment slack

    auto xwBytes  = [&](size_t tc) { return (size_t)512 * tc * 1024 * 4; };
    auto actBytes = [&](size_t t)  { return (size_t)512 * t * (256 + 128 + 64) * 2 * 2; };

    int Tc = 256; bool fullAct = true;
    while (Tc > 8 && fixed + xwBytes(Tc) + actBytes(256) > ws_size) Tc >>= 1;
    if (fixed + xwBytes(Tc) + actBytes(256) > ws_size) {
        fullAct = false; Tc = 32;
        while (Tc > 1 && fixed + xwBytes(Tc) + actBytes(Tc) > ws_size) Tc >>= 1;
    }
    int nc = 256 / Tc;
    size_t Tact = fullAct ? 256 : (size_t)Tc;
    // duplicate-launch timing is only safe when state is never re-read
    const bool dupRec = (nc == 1);

    // ---- allocate --------------------------------------------------------
    size_t off = 0;
    auto alloc = [&](size_t bytes) -> char* {
        char* p = (char*)d_ws + off;
        off = (off + bytes + 15) & ~15ull;
        return p;
    };
    float* xw = (float*)alloc(xwBytes(Tc));
    short *actHi[4], *actLo[4];
    actHi[0] = actLo[0] = nullptr;
    for (int l = 1; l < 4; ++l) {
        size_t b = (size_t)512 * Tact * FIN[l] * 2;
        actHi[l] = (short*)alloc(b);
        actLo[l] = (short*)alloc(b);
    }
    float *hb[4], *cb[4];
    for (int l = 0; l < 4; ++l) { hb[l] = (float*)alloc(hB[l]); cb[l] = (float*)alloc(hB[l]); }
    half_t* uth[2]; float* ut[2];
    for (int l = 0; l < 2; ++l) uth[l] = (half_t*)alloc(uthB[l]);
    for (int l = 0; l < 2; ++l) ut[l] = (float*)alloc(utB[l]);
    short *whi[4], *wlo[4];
    for (int l = 0; l < 4; ++l) { whi[l] = (short*)alloc(wB[l]); wlo[l] = (short*)alloc(wB[l]); }

    // ---- one-time prep ---------------------------------------------------
    for (int l = 0; l < 4; ++l) {
        int n = FIN[l] * 4 * HS[l];
        w_split<<<dim3((n + 255) / 256), dim3(256), 0, stream>>>(W[l], whi[l], wlo[l], FIN[l], 4 * HS[l]);
    }
    for (int l = 0; l < 2; ++l) {
        int n = HS[l] * 4 * HS[l];
        u_chunk_h<<<dim3((n + 255) / 256), dim3(256), 0, stream>>>(U[l], uth[l], HS[l], 4 * HS[l]);
    }
    for (int l = 0; l < 2; ++l) {
        int n = HS[l + 2] * 4 * HS[l + 2];
        u_chunk<<<dim3((n + 255) / 256), dim3(256), 0, stream>>>(U[l + 2], ut[l], HS[l + 2], 4 * HS[l + 2]);
    }

    // ---- time-chunk-interleaved layer sweep -----------------------------
    for (int c = 0; c < nc; ++c) {
        int t0 = c * Tc;
        for (int l = 0; l < 4; ++l) {
            int K = FIN[l], N4 = 4 * HS[l];
            dim3 gg((512 * Tc) / 64, N4 / 64);

            if (l == 0) {
                const float* Abase = state + (size_t)t0 * 128;
                gemm_bf16<true><<<gg, dim3(256), 0, stream>>>(
                    (const void*)Abase, nullptr, nullptr, (size_t)256 * 128,
                    whi[0], wlo[0], bi[0], xw, K, N4, Tc);
            } else {
                size_t aOff = fullAct ? (size_t)t0 * K : 0;
                size_t aStride = fullAct ? (size_t)256 * K : (size_t)Tc * K;
                gemm_bf16<false><<<gg, dim3(256), 0, stream>>>(
                    nullptr, (const void*)(actHi[l] + aOff), (const void*)(actLo[l] + aOff),
                    aStride, whi[l], wlo[l], bi[l], xw, K, N4, Tc);
            }

            short *oHi = nullptr, *oLo = nullptr;
            size_t oStride = 0;
            if (l < 3) {
                size_t oOff = fullAct ? (size_t)t0 * HS[l] : 0;
                oStride = fullAct ? (size_t)256 * HS[l] : (size_t)Tc * HS[l];
                oHi = actHi[l + 1] + oOff;
                oLo = actLo[l + 1] + oOff;
            }

            const int reps = dupRec ? 2 : 1;   // r14: measure rec share
            for (int rep = 0; rep < reps; ++rep) {
                if (l == 0)
                    lstm_rec_h<256, 4, 2><<<dim3(128), dim3(512), 0, stream>>>(
                        xw, (const uint2*)uth[0], g[0], be[0], mm[0], vv[0],
                        oHi, oLo, oStride, hb[0], cb[0], t0, Tc);
                else if (l == 1)
                    lstm_rec_h<128, 4, 4><<<dim3(128), dim3(512), 0, stream>>>(
                        xw, (const uint2*)uth[1], g[1], be[1], mm[1], vv[1],
                        oHi, oLo, oStride, hb[1], cb[1], t0, Tc);
                else if (l == 2)
                    lstm_rec32<64, 4, 4, false><<<dim3(128), dim3(256), 0, stream>>>(
                        xw, ut[0], g[2], be[2], mm[2], vv[2],
                        oHi, oLo, nullptr, oStride, hb[2], cb[2], t0, Tc);
                else
                    lstm_rec32<32, 4, 4, true><<<dim3(128), dim3(128), 0, stream>>>(
                        xw, ut[1], g[3], be[3], mm[3], vv[3],
                        nullptr, nullptr, (float*)d_out, 0, hb[3], cb[3], t0, Tc);
            }
        }
    }
}